// Round 15
// baseline (435.717 us; speedup 1.0000x reference)
//
#include <hip/hip_runtime.h>
#include <math.h>

#define N_NODES 100000
#define N_EDGES 500000
#define BATCH   8192
#define NBLK    98   // ceil(N_NODES / 1024)
#define HISTX   512  // hist-role blocks per graph in fh_all
#define FEATX   256  // feat-role blocks per graph in fh_all

typedef __bf16 bf16;
typedef __bf16 bf16x8 __attribute__((ext_vector_type(8)));
typedef float  f32x4  __attribute__((ext_vector_type(4)));
typedef unsigned long long u64;

#define MFMA16(a, b, c) __builtin_amdgcn_mfma_f32_16x16x32_bf16((a), (b), (c), 0, 0, 0)

__device__ __forceinline__ float wave_reduce_sum(float v) {
    #pragma unroll
    for (int off = 32; off; off >>= 1) v += __shfl_xor(v, off);
    return v;
}

__device__ __forceinline__ float fast_tanh(float x) {
    float e = __expf(2.f * x);
    return 1.f - 2.f / (e + 1.f);
}

__device__ __forceinline__ float b2f(unsigned short u) {
    return __int_as_float(((int)u) << 16);
}

// MERGED feat + hist (R12/R13-proven). Single-shard hist: R10 proved shards
// are a no-op on the memory-side atomic floor; R14 proved XCD-local
// agent-scope atomics do NOT move the floor either.
__global__ void __launch_bounds__(256, 6)
fh_all(const float* __restrict__ uf, const float* __restrict__ itf,
       const float* __restrict__ uW, const float* __restrict__ iW,
       const float* __restrict__ ual, const float* __restrict__ ial,
       const float* __restrict__ uar, const float* __restrict__ iar,
       bf16* __restrict__ feat, float* __restrict__ el, float* __restrict__ er,
       const int* __restrict__ udst, const int* __restrict__ idst,
       int* __restrict__ cnt, int* __restrict__ rank, int E, int N) {
    __shared__ bf16x8 ldsW[8][64];   // feat role only
    const int g = blockIdx.y;
    if (blockIdx.x < HISTX) {
        // ---- hist role: counting + rank capture, 4 atomics in flight ----
        const int* dst = ((g < 2) ? udst : idst) + (size_t)(g & 1) * E;
        int* cntg = cnt + (size_t)g * N;
        int* rk = rank + (size_t)g * E;
        const int tid = blockIdx.x * blockDim.x + threadIdx.x;
        const int stride = HISTX * blockDim.x;
        for (int i0 = tid; i0 < E; i0 += 4 * stride) {
            const int i1 = i0 + stride, i2 = i0 + 2 * stride, i3 = i0 + 3 * stride;
            int d0 = dst[i0];
            int d1 = (i1 < E) ? dst[i1] : 0;
            int d2 = (i2 < E) ? dst[i2] : 0;
            int d3 = (i3 < E) ? dst[i3] : 0;
            int r0 = 0, r1 = 0, r2 = 0, r3 = 0;
            r0 = atomicAdd(&cntg[d0], 1);
            if (i1 < E) r1 = atomicAdd(&cntg[d1], 1);
            if (i2 < E) r2 = atomicAdd(&cntg[d2], 1);
            if (i3 < E) r3 = atomicAdd(&cntg[d3], 1);
            rk[i0] = r0;
            if (i1 < E) rk[i1] = r1;
            if (i2 < E) rk[i2] = r2;
            if (i3 < E) rk[i3] = r3;
        }
        return;
    }
    // ---- feat role: feat[g] = h @ W[g] (MFMA), one graph per block ----
    const int t = g >> 1, m = g & 1;
    const int fx = (int)blockIdx.x - HISTX;          // 0..FEATX-1
    const float* h   = t ? itf : uf;
    const float* Wm  = (t ? iW : uW) + (size_t)m * 4096;
    const float* alb = (t ? ial : ual) + m * 64;
    const float* arb = (t ? iar : uar) + m * 64;
    for (int f = threadIdx.x; f < 8 * 64; f += blockDim.x) {
        int id = f >> 6, l = f & 63;
        int lc = l & 15, lq = l >> 4;
        int nt = id >> 1, kf = id & 1;
        bf16x8 v;
        #pragma unroll
        for (int j = 0; j < 8; ++j)
            v[j] = (bf16)Wm[(kf * 32 + lq * 8 + j) * 64 + nt * 16 + lc];
        ldsW[id][l] = v;
    }
    __syncthreads();
    const int lane = threadIdx.x & 63, wave = threadIdx.x >> 6, wpb = blockDim.x >> 6;
    const int c = lane & 15, q = lane >> 4;
    float alv[4], arv[4];
    #pragma unroll
    for (int nt = 0; nt < 4; ++nt) {
        alv[nt] = alb[nt * 16 + c];
        arv[nt] = arb[nt * 16 + c];
    }
    const f32x4 zf = {0.f, 0.f, 0.f, 0.f};
    const int tiles = N >> 4;
    bf16* fg   = feat + (size_t)g * N * 64;
    float* elg = el + (size_t)g * N;
    float* erg = er + (size_t)g * N;
    for (int tile = fx * wpb + wave; tile < tiles; tile += FEATX * wpb) {
        const float* hr = h + (size_t)(tile * 16 + c) * 64 + q * 8;
        f32x4 v0 = *(const f32x4*)hr;
        f32x4 v1 = *(const f32x4*)(hr + 4);
        f32x4 v2 = *(const f32x4*)(hr + 32);
        f32x4 v3 = *(const f32x4*)(hr + 36);
        bf16x8 a0, a1;
        #pragma unroll
        for (int j = 0; j < 4; ++j) {
            a0[j] = (bf16)v0[j]; a0[j + 4] = (bf16)v1[j];
            a1[j] = (bf16)v2[j]; a1[j + 4] = (bf16)v3[j];
        }
        f32x4 acc[4];
        #pragma unroll
        for (int nt = 0; nt < 4; ++nt) {
            acc[nt] = zf;
            acc[nt] = MFMA16(a0, ldsW[nt * 2][lane], acc[nt]);
            acc[nt] = MFMA16(a1, ldsW[nt * 2 + 1][lane], acc[nt]);
        }
        #pragma unroll
        for (int nt = 0; nt < 4; ++nt)
            #pragma unroll
            for (int r = 0; r < 4; ++r)
                fg[(size_t)(tile * 16 + q * 4 + r) * 64 + nt * 16 + c] = (bf16)acc[nt][r];
        #pragma unroll
        for (int r = 0; r < 4; ++r) {
            float se = 0.f, sr = 0.f;
            #pragma unroll
            for (int nt = 0; nt < 4; ++nt) {
                se = fmaf(acc[nt][r], alv[nt], se);
                sr = fmaf(acc[nt][r], arv[nt], sr);
            }
            #pragma unroll
            for (int off = 1; off < 16; off <<= 1) {
                se += __shfl_xor(se, off);
                sr += __shfl_xor(sr, off);
            }
            if (c == 0) {
                elg[tile * 16 + q * 4 + r] = se;
                erg[tile * 16 + q * 4 + r] = sr;
            }
        }
    }
}

// ONE-KERNEL exclusive scan via decoupled lookback (R13-proven).
// status word: (value<<2) | state; state 0=invalid 1=aggregate 2=prefix.
__global__ void __launch_bounds__(1024)
scan_fused(const int* __restrict__ cnt, int* __restrict__ offsets,
           u64* __restrict__ status, float* __restrict__ wsum, int N) {
    const int g = blockIdx.y, b = blockIdx.x;
    u64* stg = status + g * 128;
    __shared__ int sh[1024];
    __shared__ int total_s, excl_s;
    const int tid = (int)threadIdx.x;
    const int i = b * 1024 + tid;
    int v = (i < N) ? cnt[(size_t)g * N + i] : 0;
    sh[tid] = v;
    __syncthreads();
    for (int off = 1; off < 1024; off <<= 1) {
        int tv = (tid >= off) ? sh[tid - off] : 0;
        __syncthreads();
        sh[tid] += tv;
        __syncthreads();
    }
    int incl = sh[tid];
    if (tid == 1023) total_s = incl;
    __syncthreads();
    const int total = total_s;
    if (tid == 0) {
        if (b == 0) {
            atomicExch(&stg[0], ((u64)total << 2) | 2ull);   // PREFIX
            excl_s = 0;
        } else {
            atomicExch(&stg[b], ((u64)total << 2) | 1ull);   // AGGREGATE
            int excl = 0, pb = b - 1;
            while (true) {
                u64 w = atomicAdd(&stg[pb], 0ull);           // atomic load
                int st = (int)(w & 3ull);
                if (st == 0) { __builtin_amdgcn_s_sleep(1); continue; }
                excl += (int)(w >> 2);
                if (st == 2) break;
                --pb;
            }
            atomicExch(&stg[b], ((u64)(excl + total) << 2) | 2ull);  // PREFIX
            excl_s = excl;
        }
        if (b == 0 && g == 0) { wsum[0] = 0.f; wsum[1] = 0.f; wsum[2] = 0.f; wsum[3] = 0.f; }
    }
    __syncthreads();
    const int excl = excl_s;
    if (i < N) offsets[(size_t)g * (N + 1) + i] = excl + incl - v;
    if (b == NBLK - 1 && tid == 1023) offsets[(size_t)g * (N + 1) + N] = excl + incl;
}

// Atomic-free scatter, 4x unrolled: pos = offsets[d] + rank[i].
__global__ void scatter_all(const int* __restrict__ usrc, const int* __restrict__ udst,
                            const int* __restrict__ isrc, const int* __restrict__ idst,
                            const float* __restrict__ el, const float* __restrict__ er,
                            const int* __restrict__ offsets, const int* __restrict__ rank,
                            int2* __restrict__ epack, int E, int N) {
    const int g = blockIdx.y;
    const int* src = ((g < 2) ? usrc : isrc) + (size_t)(g & 1) * E;
    const int* dst = ((g < 2) ? udst : idst) + (size_t)(g & 1) * E;
    const float* elg = el + (size_t)g * N;
    const float* erg = er + (size_t)g * N;
    const int* offg = offsets + (size_t)g * (N + 1);
    const int* rk = rank + (size_t)g * E;
    int2* ep = epack + (size_t)g * E;
    const int tid = blockIdx.x * blockDim.x + threadIdx.x;
    const int stride = gridDim.x * blockDim.x;
    for (int i0 = tid; i0 < E; i0 += 4 * stride) {
        #pragma unroll
        for (int u = 0; u < 4; ++u) {
            const int i = i0 + u * stride;
            if (i < E) {
                int s = src[i], d = dst[i];
                int pos = offg[d] + rk[i];
                float e = elg[s] + erg[d];
                e = (e >= 0.f) ? e : 0.2f * e;
                ep[pos] = make_int2(s << 7, __float_as_int(__expf(e)));
            }
        }
    }
}

// wave-per-node: den + weighted aggregate + elu(+b).  (R8-proven structure)
__global__ void agg_all(const unsigned short* __restrict__ feat,
                        const float* __restrict__ ub, const float* __restrict__ ib,
                        const int* __restrict__ offsets, const int2* __restrict__ epack,
                        bf16* __restrict__ z, int E, int N) {
    const int g = blockIdx.y;
    const char* featg = (const char*)(feat + (size_t)g * N * 64);
    const float* bv = ((g < 2) ? ub : ib) + (g & 1) * 64;
    const int* offg = offsets + (size_t)g * (N + 1);
    const int2* ep = epack + (size_t)g * E;
    bf16* zg = z + (size_t)g * N * 64;
    const int lane = threadIdx.x & 63, wave = threadIdx.x >> 6, wpb = blockDim.x >> 6;
    const int lane2 = lane * 2;
    const float bl = bv[lane];
    for (int node0 = blockIdx.x * wpb + wave; node0 < N; node0 += gridDim.x * wpb) {
        const int node = __builtin_amdgcn_readfirstlane(node0);
        const int beg = __builtin_amdgcn_readfirstlane(offg[node]);
        const int end = __builtin_amdgcn_readfirstlane(offg[node + 1]);
        float l = 0.f, acc0 = 0.f, acc1 = 0.f;
        int i = beg;
        for (; i + 4 <= end; i += 4) {
            int2 p0 = ep[i], p1 = ep[i + 1], p2 = ep[i + 2], p3 = ep[i + 3];
            float f0 = b2f(*(const unsigned short*)(featg + (p0.x + lane2)));
            float f1 = b2f(*(const unsigned short*)(featg + (p1.x + lane2)));
            float f2 = b2f(*(const unsigned short*)(featg + (p2.x + lane2)));
            float f3 = b2f(*(const unsigned short*)(featg + (p3.x + lane2)));
            float w0 = __int_as_float(p0.y), w1 = __int_as_float(p1.y);
            float w2 = __int_as_float(p2.y), w3 = __int_as_float(p3.y);
            l += (w0 + w1) + (w2 + w3);
            acc0 = fmaf(w0, f0, acc0);
            acc1 = fmaf(w1, f1, acc1);
            acc0 = fmaf(w2, f2, acc0);
            acc1 = fmaf(w3, f3, acc1);
        }
        for (; i < end; ++i) {
            int2 p = ep[i];
            float w = __int_as_float(p.y);
            l += w;
            acc0 = fmaf(w, b2f(*(const unsigned short*)(featg + (p.x + lane2))), acc0);
        }
        float acc = acc0 + acc1;
        float o = acc / (l + 1e-9f);
        float zz = o + bl;
        zz = (zz > 0.f) ? zz : expm1f(zz);
        zg[(size_t)node * 64 + lane] = (bf16)zz;
    }
}

// wsum[g] += sum_n tanh(z[g,n] @ W1 + b1) @ W2 -- MFMA; W1 fragments in LDS.
// Grid raised 256->768 blocks/graph: at 256 the z-stream (51.2MB at only
// ~1.8TB/s) was latency-under-parallelized (~6 tiles/wave).
__global__ void __launch_bounds__(256, 4)
sem_mfma(const bf16* __restrict__ z,
         const float* __restrict__ uW1, const float* __restrict__ iW1,
         const float* __restrict__ ub1, const float* __restrict__ ib1,
         const float* __restrict__ uW2, const float* __restrict__ iW2,
         float* __restrict__ wsum, int N) {
    const int g = blockIdx.y, t = g >> 1;
    const float* W1 = t ? iW1 : uW1;
    const float* b1 = t ? ib1 : ub1;
    const float* W2 = t ? iW2 : uW2;
    __shared__ bf16x8 ldsW[16][64];   // id = nt*2+kf
    for (int f = threadIdx.x; f < 16 * 64; f += blockDim.x) {
        int id = f >> 6, l = f & 63;
        int lc = l & 15, lq = l >> 4;
        int nt = id >> 1, kf = id & 1;
        bf16x8 v;
        #pragma unroll
        for (int j = 0; j < 8; ++j)
            v[j] = (bf16)W1[(kf * 32 + lq * 8 + j) * 128 + nt * 16 + lc];
        ldsW[id][l] = v;
    }
    __syncthreads();
    const int lane = threadIdx.x & 63, wave = threadIdx.x >> 6, wpb = blockDim.x >> 6;
    const int c = lane & 15, q = lane >> 4;
    float b1v[8], w2v[8];
    #pragma unroll
    for (int nt = 0; nt < 8; ++nt) { b1v[nt] = b1[nt * 16 + c]; w2v[nt] = W2[nt * 16 + c]; }
    const bf16* zg = z + (size_t)g * N * 64;
    const f32x4 zf = {0.f, 0.f, 0.f, 0.f};
    float local = 0.f;
    const int tiles = N >> 4;
    for (int tile = blockIdx.x * wpb + wave; tile < tiles; tile += gridDim.x * wpb) {
        const bf16* zr = zg + (size_t)(tile * 16 + c) * 64;
        bf16x8 a0 = *(const bf16x8*)(zr + q * 8);
        bf16x8 a1 = *(const bf16x8*)(zr + 32 + q * 8);
        f32x4 acc[8];
        #pragma unroll
        for (int nt = 0; nt < 8; ++nt) {
            acc[nt] = zf;
            acc[nt] = MFMA16(a0, ldsW[nt * 2][lane], acc[nt]);
            acc[nt] = MFMA16(a1, ldsW[nt * 2 + 1][lane], acc[nt]);
        }
        #pragma unroll
        for (int nt = 0; nt < 8; ++nt)
            #pragma unroll
            for (int r = 0; r < 4; ++r)
                local += w2v[nt] * fast_tanh(acc[nt][r] + b1v[nt]);
    }
    local = wave_reduce_sum(local);
    if (lane == 0) atomicAdd(&wsum[g], local);
}

// gather + beta-combine + proj + relu + layernorm for indexed rows
__global__ void out_all(const int* __restrict__ uidx, const int* __restrict__ iidx,
                        const int* __restrict__ nidx, const bf16* __restrict__ z,
                        const float* __restrict__ wsum,
                        const float* __restrict__ userW, const float* __restrict__ userb,
                        const float* __restrict__ itemW, const float* __restrict__ itemb,
                        const float* __restrict__ ln_g, const float* __restrict__ ln_b,
                        float* __restrict__ out, int N, int B) {
    const int grp = blockIdx.y;
    const int t = (grp == 0) ? 0 : 1;
    const float* Wt = t ? itemW : userW;
    const float* bt = t ? itemb : userb;
    const int* idx = (grp == 0) ? uidx : ((grp == 1) ? iidx : nidx);
    const bf16* zg = z + (size_t)(t * 2) * N * 64;
    const int lane = threadIdx.x & 63, wave = threadIdx.x >> 6, wpb = blockDim.x >> 6;
    float Wc[64];
    #pragma unroll
    for (int k = 0; k < 64; ++k) Wc[k] = Wt[k * 64 + lane];
    const float btl = bt[lane], gl = ln_g[lane], lbl = ln_b[lane];
    const float invN = 1.f / (float)N;
    float w0 = wsum[t * 2] * invN, w1 = wsum[t * 2 + 1] * invN;
    float mx = fmaxf(w0, w1);
    float e0 = __expf(w0 - mx), e1 = __expf(w1 - mx);
    float bsum = e0 + e1;
    float beta0 = e0 / bsum, beta1 = e1 / bsum;
    for (int r = blockIdx.x * wpb + wave; r < B; r += gridDim.x * wpb) {
        const int urr = __builtin_amdgcn_readfirstlane(r);
        const int un = __builtin_amdgcn_readfirstlane(idx[urr]);
        float e = beta0 * (float)zg[(size_t)un * 64 + lane]
                + beta1 * (float)zg[(size_t)(N + un) * 64 + lane];
        float y = btl;
        #pragma unroll
        for (int k = 0; k < 64; ++k) y = fmaf(__shfl(e, k), Wc[k], y);
        y = fmaxf(y, 0.f);
        float mu = wave_reduce_sum(y) * (1.f / 64.f);
        float d = y - mu;
        float var = wave_reduce_sum(d * d) * (1.f / 64.f);
        out[(size_t)(grp * B + r) * 64 + lane] = gl * d / sqrtf(var + 1e-5f) + lbl;
    }
}

extern "C" void kernel_launch(void* const* d_in, const int* in_sizes, int n_in,
                              void* d_out, int out_size, void* d_ws, size_t ws_size,
                              hipStream_t stream) {
    const int* user_idx = (const int*)d_in[0];
    const int* item_idx = (const int*)d_in[1];
    const int* neg_idx  = (const int*)d_in[2];
    const float* user_feat = (const float*)d_in[3];
    const float* item_feat = (const float*)d_in[4];
    const int* u_src = (const int*)d_in[5];
    const int* u_dst = (const int*)d_in[6];
    const int* i_src = (const int*)d_in[7];
    const int* i_dst = (const int*)d_in[8];
    const float* u_W  = (const float*)d_in[9];
    const float* u_al = (const float*)d_in[10];
    const float* u_ar = (const float*)d_in[11];
    const float* u_b  = (const float*)d_in[12];
    const float* i_W  = (const float*)d_in[13];
    const float* i_al = (const float*)d_in[14];
    const float* i_ar = (const float*)d_in[15];
    const float* i_b  = (const float*)d_in[16];
    const float* u_saW1 = (const float*)d_in[17];
    const float* u_sab1 = (const float*)d_in[18];
    const float* u_saW2 = (const float*)d_in[19];
    const float* i_saW1 = (const float*)d_in[20];
    const float* i_sab1 = (const float*)d_in[21];
    const float* i_saW2 = (const float*)d_in[22];
    const float* userW = (const float*)d_in[23];
    const float* userb = (const float*)d_in[24];
    const float* itemW = (const float*)d_in[25];
    const float* itemb = (const float*)d_in[26];
    const float* ln_g  = (const float*)d_in[27];
    const float* ln_b  = (const float*)d_in[28];

    const int N = N_NODES, E = N_EDGES, B = BATCH;

    char* ws = (char*)d_ws;
    size_t off = 0;
    auto alloc = [&](size_t bytes) -> char* {
        char* p = ws + off;
        off += (bytes + 255) & ~(size_t)255;
        return p;
    };
    bf16* feat   = (bf16*)alloc((size_t)4 * N * 64 * 2);    // 51.2 MB
    bf16* z      = (bf16*)alloc((size_t)4 * N * 64 * 2);    // 51.2 MB
    float* el    = (float*)alloc((size_t)4 * N * 4);
    float* er    = (float*)alloc((size_t)4 * N * 4);
    int* offsets = (int*)alloc((size_t)4 * (N + 1) * 4);
    int* cnt     = (int*)alloc((size_t)4 * N * 4);          // 1.6 MB (zeroed with status)
    u64* status  = (u64*)alloc((size_t)4 * 128 * 8);        // 4 KB, contiguous after cnt
    int* rank    = (int*)alloc((size_t)4 * E * 4);          // 8 MB
    int2* epack  = (int2*)alloc((size_t)4 * E * 8);         // 16 MB
    float* wsum  = (float*)alloc(16);
    (void)ws_size; (void)in_sizes; (void)n_in; (void)out_size;

    dim3 blk(256);
    // cnt (1.6MB, 256B-aligned size) and status (4KB) are contiguous: one memset.
    hipMemsetAsync(cnt, 0, (size_t)4 * N * 4 + 4096, stream);

    fh_all<<<dim3(HISTX + FEATX, 4), blk, 0, stream>>>(
        user_feat, item_feat, u_W, i_W, u_al, i_al, u_ar, i_ar,
        feat, el, er, u_dst, i_dst, cnt, rank, E, N);
    scan_fused<<<dim3(NBLK, 4), dim3(1024), 0, stream>>>(cnt, offsets, status, wsum, N);
    scatter_all<<<dim3(1024, 4), blk, 0, stream>>>(u_src, u_dst, i_src, i_dst,
                                                   el, er, offsets, rank, epack, E, N);
    agg_all<<<dim3(2048, 4), blk, 0, stream>>>((const unsigned short*)feat, u_b, i_b,
                                               offsets, epack, z, E, N);
    sem_mfma<<<dim3(768, 4), blk, 0, stream>>>(z, u_saW1, i_saW1, u_sab1, i_sab1,
                                               u_saW2, i_saW2, wsum, N);
    out_all<<<dim3(512, 3), blk, 0, stream>>>(user_idx, item_idx, neg_idx, z, wsum,
                                              userW, userb, itemW, itemb, ln_g, ln_b,
                                              (float*)d_out, N, B);
}

// Round 16
// 307.379 us; speedup vs baseline: 1.4175x; 1.4175x over previous
//
#include <hip/hip_runtime.h>
#include <math.h>

#define N_NODES 100000
#define N_EDGES 500000
#define BATCH   8192
#define NBLK    98   // ceil(N_NODES / 1024)
#define HISTX   512  // hist-role blocks per graph in fh_all
#define FEATX   256  // feat-role blocks per graph in fh_all

typedef __bf16 bf16;
typedef __bf16 bf16x8 __attribute__((ext_vector_type(8)));
typedef float  f32x4  __attribute__((ext_vector_type(4)));
typedef unsigned long long u64;

#define MFMA16(a, b, c) __builtin_amdgcn_mfma_f32_16x16x32_bf16((a), (b), (c), 0, 0, 0)

__device__ __forceinline__ float wave_reduce_sum(float v) {
    #pragma unroll
    for (int off = 32; off; off >>= 1) v += __shfl_xor(v, off);
    return v;
}

__device__ __forceinline__ float fast_tanh(float x) {
    float e = __expf(2.f * x);
    return 1.f - 2.f / (e + 1.f);
}

__device__ __forceinline__ float b2f(unsigned short u) {
    return __int_as_float(((int)u) << 16);
}

// MERGED feat + hist (R12/R13-proven). Single-shard hist: R10 proved shards
// are a no-op on the memory-side atomic floor; R14 proved XCD-local
// agent-scope atomics do NOT move the floor either.
__global__ void __launch_bounds__(256, 6)
fh_all(const float* __restrict__ uf, const float* __restrict__ itf,
       const float* __restrict__ uW, const float* __restrict__ iW,
       const float* __restrict__ ual, const float* __restrict__ ial,
       const float* __restrict__ uar, const float* __restrict__ iar,
       bf16* __restrict__ feat, float* __restrict__ el, float* __restrict__ er,
       const int* __restrict__ udst, const int* __restrict__ idst,
       int* __restrict__ cnt, int* __restrict__ rank, int E, int N) {
    __shared__ bf16x8 ldsW[8][64];   // feat role only
    const int g = blockIdx.y;
    if (blockIdx.x < HISTX) {
        // ---- hist role: counting + rank capture, 4 atomics in flight ----
        const int* dst = ((g < 2) ? udst : idst) + (size_t)(g & 1) * E;
        int* cntg = cnt + (size_t)g * N;
        int* rk = rank + (size_t)g * E;
        const int tid = blockIdx.x * blockDim.x + threadIdx.x;
        const int stride = HISTX * blockDim.x;
        for (int i0 = tid; i0 < E; i0 += 4 * stride) {
            const int i1 = i0 + stride, i2 = i0 + 2 * stride, i3 = i0 + 3 * stride;
            int d0 = dst[i0];
            int d1 = (i1 < E) ? dst[i1] : 0;
            int d2 = (i2 < E) ? dst[i2] : 0;
            int d3 = (i3 < E) ? dst[i3] : 0;
            int r0 = 0, r1 = 0, r2 = 0, r3 = 0;
            r0 = atomicAdd(&cntg[d0], 1);
            if (i1 < E) r1 = atomicAdd(&cntg[d1], 1);
            if (i2 < E) r2 = atomicAdd(&cntg[d2], 1);
            if (i3 < E) r3 = atomicAdd(&cntg[d3], 1);
            rk[i0] = r0;
            if (i1 < E) rk[i1] = r1;
            if (i2 < E) rk[i2] = r2;
            if (i3 < E) rk[i3] = r3;
        }
        return;
    }
    // ---- feat role: feat[g] = h @ W[g] (MFMA), one graph per block ----
    const int t = g >> 1, m = g & 1;
    const int fx = (int)blockIdx.x - HISTX;          // 0..FEATX-1
    const float* h   = t ? itf : uf;
    const float* Wm  = (t ? iW : uW) + (size_t)m * 4096;
    const float* alb = (t ? ial : ual) + m * 64;
    const float* arb = (t ? iar : uar) + m * 64;
    for (int f = threadIdx.x; f < 8 * 64; f += blockDim.x) {
        int id = f >> 6, l = f & 63;
        int lc = l & 15, lq = l >> 4;
        int nt = id >> 1, kf = id & 1;
        bf16x8 v;
        #pragma unroll
        for (int j = 0; j < 8; ++j)
            v[j] = (bf16)Wm[(kf * 32 + lq * 8 + j) * 64 + nt * 16 + lc];
        ldsW[id][l] = v;
    }
    __syncthreads();
    const int lane = threadIdx.x & 63, wave = threadIdx.x >> 6, wpb = blockDim.x >> 6;
    const int c = lane & 15, q = lane >> 4;
    float alv[4], arv[4];
    #pragma unroll
    for (int nt = 0; nt < 4; ++nt) {
        alv[nt] = alb[nt * 16 + c];
        arv[nt] = arb[nt * 16 + c];
    }
    const f32x4 zf = {0.f, 0.f, 0.f, 0.f};
    const int tiles = N >> 4;
    bf16* fg   = feat + (size_t)g * N * 64;
    float* elg = el + (size_t)g * N;
    float* erg = er + (size_t)g * N;
    for (int tile = fx * wpb + wave; tile < tiles; tile += FEATX * wpb) {
        const float* hr = h + (size_t)(tile * 16 + c) * 64 + q * 8;
        f32x4 v0 = *(const f32x4*)hr;
        f32x4 v1 = *(const f32x4*)(hr + 4);
        f32x4 v2 = *(const f32x4*)(hr + 32);
        f32x4 v3 = *(const f32x4*)(hr + 36);
        bf16x8 a0, a1;
        #pragma unroll
        for (int j = 0; j < 4; ++j) {
            a0[j] = (bf16)v0[j]; a0[j + 4] = (bf16)v1[j];
            a1[j] = (bf16)v2[j]; a1[j + 4] = (bf16)v3[j];
        }
        f32x4 acc[4];
        #pragma unroll
        for (int nt = 0; nt < 4; ++nt) {
            acc[nt] = zf;
            acc[nt] = MFMA16(a0, ldsW[nt * 2][lane], acc[nt]);
            acc[nt] = MFMA16(a1, ldsW[nt * 2 + 1][lane], acc[nt]);
        }
        #pragma unroll
        for (int nt = 0; nt < 4; ++nt)
            #pragma unroll
            for (int r = 0; r < 4; ++r)
                fg[(size_t)(tile * 16 + q * 4 + r) * 64 + nt * 16 + c] = (bf16)acc[nt][r];
        #pragma unroll
        for (int r = 0; r < 4; ++r) {
            float se = 0.f, sr = 0.f;
            #pragma unroll
            for (int nt = 0; nt < 4; ++nt) {
                se = fmaf(acc[nt][r], alv[nt], se);
                sr = fmaf(acc[nt][r], arv[nt], sr);
            }
            #pragma unroll
            for (int off = 1; off < 16; off <<= 1) {
                se += __shfl_xor(se, off);
                sr += __shfl_xor(sr, off);
            }
            if (c == 0) {
                elg[tile * 16 + q * 4 + r] = se;
                erg[tile * 16 + q * 4 + r] = sr;
            }
        }
    }
}

// ONE-KERNEL exclusive scan via decoupled lookback (R13-proven).
// status word: (value<<2) | state; state 0=invalid 1=aggregate 2=prefix.
__global__ void __launch_bounds__(1024)
scan_fused(const int* __restrict__ cnt, int* __restrict__ offsets,
           u64* __restrict__ status, float* __restrict__ wsum, int N) {
    const int g = blockIdx.y, b = blockIdx.x;
    u64* stg = status + g * 128;
    __shared__ int sh[1024];
    __shared__ int total_s, excl_s;
    const int tid = (int)threadIdx.x;
    const int i = b * 1024 + tid;
    int v = (i < N) ? cnt[(size_t)g * N + i] : 0;
    sh[tid] = v;
    __syncthreads();
    for (int off = 1; off < 1024; off <<= 1) {
        int tv = (tid >= off) ? sh[tid - off] : 0;
        __syncthreads();
        sh[tid] += tv;
        __syncthreads();
    }
    int incl = sh[tid];
    if (tid == 1023) total_s = incl;
    __syncthreads();
    const int total = total_s;
    if (tid == 0) {
        if (b == 0) {
            atomicExch(&stg[0], ((u64)total << 2) | 2ull);   // PREFIX
            excl_s = 0;
        } else {
            atomicExch(&stg[b], ((u64)total << 2) | 1ull);   // AGGREGATE
            int excl = 0, pb = b - 1;
            while (true) {
                u64 w = atomicAdd(&stg[pb], 0ull);           // atomic load
                int st = (int)(w & 3ull);
                if (st == 0) { __builtin_amdgcn_s_sleep(1); continue; }
                excl += (int)(w >> 2);
                if (st == 2) break;
                --pb;
            }
            atomicExch(&stg[b], ((u64)(excl + total) << 2) | 2ull);  // PREFIX
            excl_s = excl;
        }
        if (b == 0 && g == 0) { wsum[0] = 0.f; wsum[1] = 0.f; wsum[2] = 0.f; wsum[3] = 0.f; }
    }
    __syncthreads();
    const int excl = excl_s;
    if (i < N) offsets[(size_t)g * (N + 1) + i] = excl + incl - v;
    if (b == NBLK - 1 && tid == 1023) offsets[(size_t)g * (N + 1) + N] = excl + incl;
}

// Atomic-free scatter, 4x unrolled: pos = offsets[d] + rank[i].
__global__ void scatter_all(const int* __restrict__ usrc, const int* __restrict__ udst,
                            const int* __restrict__ isrc, const int* __restrict__ idst,
                            const float* __restrict__ el, const float* __restrict__ er,
                            const int* __restrict__ offsets, const int* __restrict__ rank,
                            int2* __restrict__ epack, int E, int N) {
    const int g = blockIdx.y;
    const int* src = ((g < 2) ? usrc : isrc) + (size_t)(g & 1) * E;
    const int* dst = ((g < 2) ? udst : idst) + (size_t)(g & 1) * E;
    const float* elg = el + (size_t)g * N;
    const float* erg = er + (size_t)g * N;
    const int* offg = offsets + (size_t)g * (N + 1);
    const int* rk = rank + (size_t)g * E;
    int2* ep = epack + (size_t)g * E;
    const int tid = blockIdx.x * blockDim.x + threadIdx.x;
    const int stride = gridDim.x * blockDim.x;
    for (int i0 = tid; i0 < E; i0 += 4 * stride) {
        #pragma unroll
        for (int u = 0; u < 4; ++u) {
            const int i = i0 + u * stride;
            if (i < E) {
                int s = src[i], d = dst[i];
                int pos = offg[d] + rk[i];
                float e = elg[s] + erg[d];
                e = (e >= 0.f) ? e : 0.2f * e;
                ep[pos] = make_int2(s << 7, __float_as_int(__expf(e)));
            }
        }
    }
}

// wave-per-node: den + weighted aggregate + elu(+b).  (R8-proven structure)
__global__ void agg_all(const unsigned short* __restrict__ feat,
                        const float* __restrict__ ub, const float* __restrict__ ib,
                        const int* __restrict__ offsets, const int2* __restrict__ epack,
                        bf16* __restrict__ z, int E, int N) {
    const int g = blockIdx.y;
    const char* featg = (const char*)(feat + (size_t)g * N * 64);
    const float* bv = ((g < 2) ? ub : ib) + (g & 1) * 64;
    const int* offg = offsets + (size_t)g * (N + 1);
    const int2* ep = epack + (size_t)g * E;
    bf16* zg = z + (size_t)g * N * 64;
    const int lane = threadIdx.x & 63, wave = threadIdx.x >> 6, wpb = blockDim.x >> 6;
    const int lane2 = lane * 2;
    const float bl = bv[lane];
    for (int node0 = blockIdx.x * wpb + wave; node0 < N; node0 += gridDim.x * wpb) {
        const int node = __builtin_amdgcn_readfirstlane(node0);
        const int beg = __builtin_amdgcn_readfirstlane(offg[node]);
        const int end = __builtin_amdgcn_readfirstlane(offg[node + 1]);
        float l = 0.f, acc0 = 0.f, acc1 = 0.f;
        int i = beg;
        for (; i + 4 <= end; i += 4) {
            int2 p0 = ep[i], p1 = ep[i + 1], p2 = ep[i + 2], p3 = ep[i + 3];
            float f0 = b2f(*(const unsigned short*)(featg + (p0.x + lane2)));
            float f1 = b2f(*(const unsigned short*)(featg + (p1.x + lane2)));
            float f2 = b2f(*(const unsigned short*)(featg + (p2.x + lane2)));
            float f3 = b2f(*(const unsigned short*)(featg + (p3.x + lane2)));
            float w0 = __int_as_float(p0.y), w1 = __int_as_float(p1.y);
            float w2 = __int_as_float(p2.y), w3 = __int_as_float(p3.y);
            l += (w0 + w1) + (w2 + w3);
            acc0 = fmaf(w0, f0, acc0);
            acc1 = fmaf(w1, f1, acc1);
            acc0 = fmaf(w2, f2, acc0);
            acc1 = fmaf(w3, f3, acc1);
        }
        for (; i < end; ++i) {
            int2 p = ep[i];
            float w = __int_as_float(p.y);
            l += w;
            acc0 = fmaf(w, b2f(*(const unsigned short*)(featg + (p.x + lane2))), acc0);
        }
        float acc = acc0 + acc1;
        float o = acc / (l + 1e-9f);
        float zz = o + bl;
        zz = (zz > 0.f) ? zz : expm1f(zz);
        zg[(size_t)node * 64 + lane] = (bf16)zz;
    }
}

// wsum[g] += sum_n tanh(z[g,n] @ W1 + b1) @ W2 -- MFMA; W1 fragments in LDS.
// Grid 256/graph (R13-proven). ONE atomic per BLOCK (R15 lesson: per-wave
// same-address atomics serialize memory-side, ~50ns each -> grid-scaling tail).
__global__ void __launch_bounds__(256, 4)
sem_mfma(const bf16* __restrict__ z,
         const float* __restrict__ uW1, const float* __restrict__ iW1,
         const float* __restrict__ ub1, const float* __restrict__ ib1,
         const float* __restrict__ uW2, const float* __restrict__ iW2,
         float* __restrict__ wsum, int N) {
    const int g = blockIdx.y, t = g >> 1;
    const float* W1 = t ? iW1 : uW1;
    const float* b1 = t ? ib1 : ub1;
    const float* W2 = t ? iW2 : uW2;
    __shared__ bf16x8 ldsW[16][64];   // id = nt*2+kf
    __shared__ float red[4];
    for (int f = threadIdx.x; f < 16 * 64; f += blockDim.x) {
        int id = f >> 6, l = f & 63;
        int lc = l & 15, lq = l >> 4;
        int nt = id >> 1, kf = id & 1;
        bf16x8 v;
        #pragma unroll
        for (int j = 0; j < 8; ++j)
            v[j] = (bf16)W1[(kf * 32 + lq * 8 + j) * 128 + nt * 16 + lc];
        ldsW[id][l] = v;
    }
    __syncthreads();
    const int lane = threadIdx.x & 63, wave = threadIdx.x >> 6, wpb = blockDim.x >> 6;
    const int c = lane & 15, q = lane >> 4;
    float b1v[8], w2v[8];
    #pragma unroll
    for (int nt = 0; nt < 8; ++nt) { b1v[nt] = b1[nt * 16 + c]; w2v[nt] = W2[nt * 16 + c]; }
    const bf16* zg = z + (size_t)g * N * 64;
    const f32x4 zf = {0.f, 0.f, 0.f, 0.f};
    float local = 0.f;
    const int tiles = N >> 4;
    for (int tile = blockIdx.x * wpb + wave; tile < tiles; tile += gridDim.x * wpb) {
        const bf16* zr = zg + (size_t)(tile * 16 + c) * 64;
        bf16x8 a0 = *(const bf16x8*)(zr + q * 8);
        bf16x8 a1 = *(const bf16x8*)(zr + 32 + q * 8);
        f32x4 acc[8];
        #pragma unroll
        for (int nt = 0; nt < 8; ++nt) {
            acc[nt] = zf;
            acc[nt] = MFMA16(a0, ldsW[nt * 2][lane], acc[nt]);
            acc[nt] = MFMA16(a1, ldsW[nt * 2 + 1][lane], acc[nt]);
        }
        #pragma unroll
        for (int nt = 0; nt < 8; ++nt)
            #pragma unroll
            for (int r = 0; r < 4; ++r)
                local += w2v[nt] * fast_tanh(acc[nt][r] + b1v[nt]);
    }
    local = wave_reduce_sum(local);
    if (lane == 0) red[wave] = local;
    __syncthreads();
    if (threadIdx.x == 0) {
        float s = (red[0] + red[1]) + (red[2] + red[3]);
        atomicAdd(&wsum[g], s);
    }
}

// gather + beta-combine + proj + relu + layernorm for indexed rows
__global__ void out_all(const int* __restrict__ uidx, const int* __restrict__ iidx,
                        const int* __restrict__ nidx, const bf16* __restrict__ z,
                        const float* __restrict__ wsum,
                        const float* __restrict__ userW, const float* __restrict__ userb,
                        const float* __restrict__ itemW, const float* __restrict__ itemb,
                        const float* __restrict__ ln_g, const float* __restrict__ ln_b,
                        float* __restrict__ out, int N, int B) {
    const int grp = blockIdx.y;
    const int t = (grp == 0) ? 0 : 1;
    const float* Wt = t ? itemW : userW;
    const float* bt = t ? itemb : userb;
    const int* idx = (grp == 0) ? uidx : ((grp == 1) ? iidx : nidx);
    const bf16* zg = z + (size_t)(t * 2) * N * 64;
    const int lane = threadIdx.x & 63, wave = threadIdx.x >> 6, wpb = blockDim.x >> 6;
    float Wc[64];
    #pragma unroll
    for (int k = 0; k < 64; ++k) Wc[k] = Wt[k * 64 + lane];
    const float btl = bt[lane], gl = ln_g[lane], lbl = ln_b[lane];
    const float invN = 1.f / (float)N;
    float w0 = wsum[t * 2] * invN, w1 = wsum[t * 2 + 1] * invN;
    float mx = fmaxf(w0, w1);
    float e0 = __expf(w0 - mx), e1 = __expf(w1 - mx);
    float bsum = e0 + e1;
    float beta0 = e0 / bsum, beta1 = e1 / bsum;
    for (int r = blockIdx.x * wpb + wave; r < B; r += gridDim.x * wpb) {
        const int urr = __builtin_amdgcn_readfirstlane(r);
        const int un = __builtin_amdgcn_readfirstlane(idx[urr]);
        float e = beta0 * (float)zg[(size_t)un * 64 + lane]
                + beta1 * (float)zg[(size_t)(N + un) * 64 + lane];
        float y = btl;
        #pragma unroll
        for (int k = 0; k < 64; ++k) y = fmaf(__shfl(e, k), Wc[k], y);
        y = fmaxf(y, 0.f);
        float mu = wave_reduce_sum(y) * (1.f / 64.f);
        float d = y - mu;
        float var = wave_reduce_sum(d * d) * (1.f / 64.f);
        out[(size_t)(grp * B + r) * 64 + lane] = gl * d / sqrtf(var + 1e-5f) + lbl;
    }
}

extern "C" void kernel_launch(void* const* d_in, const int* in_sizes, int n_in,
                              void* d_out, int out_size, void* d_ws, size_t ws_size,
                              hipStream_t stream) {
    const int* user_idx = (const int*)d_in[0];
    const int* item_idx = (const int*)d_in[1];
    const int* neg_idx  = (const int*)d_in[2];
    const float* user_feat = (const float*)d_in[3];
    const float* item_feat = (const float*)d_in[4];
    const int* u_src = (const int*)d_in[5];
    const int* u_dst = (const int*)d_in[6];
    const int* i_src = (const int*)d_in[7];
    const int* i_dst = (const int*)d_in[8];
    const float* u_W  = (const float*)d_in[9];
    const float* u_al = (const float*)d_in[10];
    const float* u_ar = (const float*)d_in[11];
    const float* u_b  = (const float*)d_in[12];
    const float* i_W  = (const float*)d_in[13];
    const float* i_al = (const float*)d_in[14];
    const float* i_ar = (const float*)d_in[15];
    const float* i_b  = (const float*)d_in[16];
    const float* u_saW1 = (const float*)d_in[17];
    const float* u_sab1 = (const float*)d_in[18];
    const float* u_saW2 = (const float*)d_in[19];
    const float* i_saW1 = (const float*)d_in[20];
    const float* i_sab1 = (const float*)d_in[21];
    const float* i_saW2 = (const float*)d_in[22];
    const float* userW = (const float*)d_in[23];
    const float* userb = (const float*)d_in[24];
    const float* itemW = (const float*)d_in[25];
    const float* itemb = (const float*)d_in[26];
    const float* ln_g  = (const float*)d_in[27];
    const float* ln_b  = (const float*)d_in[28];

    const int N = N_NODES, E = N_EDGES, B = BATCH;

    char* ws = (char*)d_ws;
    size_t off = 0;
    auto alloc = [&](size_t bytes) -> char* {
        char* p = ws + off;
        off += (bytes + 255) & ~(size_t)255;
        return p;
    };
    bf16* feat   = (bf16*)alloc((size_t)4 * N * 64 * 2);    // 51.2 MB
    bf16* z      = (bf16*)alloc((size_t)4 * N * 64 * 2);    // 51.2 MB
    float* el    = (float*)alloc((size_t)4 * N * 4);
    float* er    = (float*)alloc((size_t)4 * N * 4);
    int* offsets = (int*)alloc((size_t)4 * (N + 1) * 4);
    int* cnt     = (int*)alloc((size_t)4 * N * 4);          // 1.6 MB (zeroed with status)
    u64* status  = (u64*)alloc((size_t)4 * 128 * 8);        // 4 KB, contiguous after cnt
    int* rank    = (int*)alloc((size_t)4 * E * 4);          // 8 MB
    int2* epack  = (int2*)alloc((size_t)4 * E * 8);         // 16 MB
    float* wsum  = (float*)alloc(16);
    (void)ws_size; (void)in_sizes; (void)n_in; (void)out_size;

    dim3 blk(256);
    // cnt (1.6MB, 256B-aligned size) and status (4KB) are contiguous: one memset.
    hipMemsetAsync(cnt, 0, (size_t)4 * N * 4 + 4096, stream);

    fh_all<<<dim3(HISTX + FEATX, 4), blk, 0, stream>>>(
        user_feat, item_feat, u_W, i_W, u_al, i_al, u_ar, i_ar,
        feat, el, er, u_dst, i_dst, cnt, rank, E, N);
    scan_fused<<<dim3(NBLK, 4), dim3(1024), 0, stream>>>(cnt, offsets, status, wsum, N);
    scatter_all<<<dim3(1024, 4), blk, 0, stream>>>(u_src, u_dst, i_src, i_dst,
                                                   el, er, offsets, rank, epack, E, N);
    agg_all<<<dim3(2048, 4), blk, 0, stream>>>((const unsigned short*)feat, u_b, i_b,
                                               offsets, epack, z, E, N);
    sem_mfma<<<dim3(256, 4), blk, 0, stream>>>(z, u_saW1, i_saW1, u_sab1, i_sab1,
                                               u_saW2, i_saW2, wsum, N);
    out_all<<<dim3(512, 3), blk, 0, stream>>>(user_idx, item_idx, neg_idx, z, wsum,
                                              userW, userb, itemW, itemb, ln_g, ln_b,
                                              (float*)d_out, N, B);
}